// Round 3
// baseline (108.678 us; speedup 1.0000x reference)
//
#include <hip/hip_runtime.h>
#include <hip/hip_bf16.h>
#include <hip/hip_fp16.h>

// minGRU parallel scan, B=4 L=8192 DX=512 DH=512.
// h_t = a_t h_{t-1} + b_t, a=sigmoid(-k), b=sigmoid(k)*g(p); linear-space chunked scan.
// R3: weights as fragment-ordered global (L2-resident, no LDS staging); 2-phase
// x-tile pipeline; frag-ordered half2 pk buffer for coalesced epilogue stores.

#define BB 4
#define LL 8192
#define MM (BB*LL)        // 32768 rows
#define NC 128            // chunks per batch
#define CHUNK 64          // L / NC

typedef __attribute__((ext_vector_type(8))) short bf16x8;
typedef __attribute__((ext_vector_type(4))) float f32x4;

__device__ inline unsigned f2bf(float f) {
    unsigned u = __float_as_uint(f);
    return ((u + 0x7FFFu + ((u >> 16) & 1u)) >> 16) & 0xFFFFu;
}

// f32 -> bf16 with XOR chunk-swizzle baked into the GLOBAL layout (for x):
// element [l, d] (d = seg*64 + sub*8 + e) stored at [l, seg*64 + (sub^(l&7))*8 + e].
__global__ void cvt_swz(const float* __restrict__ in, unsigned short* __restrict__ out, int rows) {
    int t = blockIdx.x * 256 + threadIdx.x;
    if (t >= rows * 64) return;
    int l = t >> 6, c = t & 63;
    int seg = c >> 3, sub = c & 7;
    int q = sub ^ (l & 7);
    const float* p = in + (size_t)l * 512 + c * 8;
    float4 v0 = *(const float4*)p;
    float4 v1 = *(const float4*)(p + 4);
    uint4 o;
    o.x = f2bf(v0.x) | (f2bf(v0.y) << 16);
    o.y = f2bf(v0.z) | (f2bf(v0.w) << 16);
    o.z = f2bf(v1.x) | (f2bf(v1.y) << 16);
    o.w = f2bf(v1.z) | (f2bf(v1.w) << 16);
    *(uint4*)(out + (size_t)l * 512 + seg * 64 + q * 8) = o;
}

// Pack both weights into MFMA B-fragment order:
// frag u = (((ntile*8 + ks)*2 + kk)*8 + nf2)*64 + lane holds W[n][k..k+8],
// n = ntile*128 + nf2*16 + (lane&15), k = ks*64 + kk*32 + (lane>>4)*8.
__global__ void cvt_wfrag(const float* __restrict__ Wz, const float* __restrict__ Wh,
                          unsigned short* __restrict__ wzf, unsigned short* __restrict__ whf) {
    int t = blockIdx.x * 256 + threadIdx.x;    // 0..65535
    int wsel = t >> 15;
    int u = t & 32767;
    int lane = u & 63, lg = lane >> 4, lr = lane & 15;
    int nf2 = (u >> 6) & 7;
    int kk = (u >> 9) & 1;
    int ks = (u >> 10) & 7;
    int ntile = (u >> 13) & 3;
    int n = ntile * 128 + nf2 * 16 + lr;
    int k = ks * 64 + kk * 32 + lg * 8;
    const float* W = wsel ? Wh : Wz;
    unsigned short* o = wsel ? whf : wzf;
    const float* p = W + (size_t)n * 512 + k;
    float4 v0 = *(const float4*)p;
    float4 v1 = *(const float4*)(p + 4);
    uint4 ov;
    ov.x = f2bf(v0.x) | (f2bf(v0.y) << 16);
    ov.y = f2bf(v0.z) | (f2bf(v0.w) << 16);
    ov.z = f2bf(v1.x) | (f2bf(v1.y) << 16);
    ov.w = f2bf(v1.z) | (f2bf(v1.w) << 16);
    *(uint4*)(o + (size_t)u * 8) = ov;
}

#define GLDS(g, l) __builtin_amdgcn_global_load_lds( \
    (const __attribute__((address_space(1))) unsigned int*)(g), \
    (__attribute__((address_space(3))) unsigned int*)(l), 16, 0, 0)

// 128x128 tile, BK=64, 4 waves, dual accumulators (k and p). Only x is LDS-staged
// (double-buffered); weight fragments stream from L2. One barrier per K-step.
__global__ __launch_bounds__(256, 2) void gemm_gate(
    const unsigned short* __restrict__ xs, const unsigned short* __restrict__ wzf,
    const unsigned short* __restrict__ whf,
    const float* __restrict__ bz, const float* __restrict__ bh,
    uint4* __restrict__ pkf, float2* __restrict__ agg)
{
    __shared__ unsigned short lx[2][128 * 64];
    const int tid = threadIdx.x;
    const int wid = tid >> 6, lane = tid & 63;
    const int lr = lane & 15, lg = lane >> 4;
    const int wm = wid >> 1, wn = wid & 1;
    const int m0 = blockIdx.x * 128;
    const int by = blockIdx.y, n0 = by * 128;

    f32x4 acck[4][4] = {};
    f32x4 accp[4][4] = {};

#define STAGE(buf, ks) do { \
    _Pragma("unroll") \
    for (int j = 0; j < 4; ++j) { \
        int off = wid * 1024 + j * 4096 + lane * 16; \
        int r = off >> 7, cb = off & 127; \
        GLDS((const char*)xs + (size_t)(m0 + r) * 1024 + (ks) * 128 + cb, \
             (char*)lx + (buf) * 16384 + off); \
    } } while (0)

    STAGE(0, 0);
    __syncthreads();

    for (int ks = 0; ks < 8; ++ks) {
        const int cur = ks & 1;
        // (1) weight fragment loads for this K-step (oldest in vmcnt queue)
        bf16x8 wzr[2][4], whr[2][4];
#pragma unroll
        for (int kk = 0; kk < 2; ++kk)
#pragma unroll
            for (int nf = 0; nf < 4; ++nf) {
                size_t fo = (((((size_t)by * 8 + ks) * 2 + kk) * 8) + wn * 4 + nf) * 512 + lane * 8;
                wzr[kk][nf] = *(const bf16x8*)(wzf + fo);
                whr[kk][nf] = *(const bf16x8*)(whf + fo);
            }
        __builtin_amdgcn_sched_barrier(0);
        // (2) prefetch next x tile into the other buffer
        if (ks < 7) STAGE(cur ^ 1, ks + 1);
        __builtin_amdgcn_sched_barrier(0);
        // (3) compute on current buffer
#pragma unroll
        for (int kk = 0; kk < 2; ++kk) {
            bf16x8 af[4];
#pragma unroll
            for (int mf = 0; mf < 4; ++mf) {
                int r = wm * 64 + mf * 16 + lr;
                int q = (kk * 4 + lg) ^ (r & 7);
                af[mf] = *(const bf16x8*)((const char*)lx + cur * 16384 + r * 128 + q * 16);
            }
#pragma unroll
            for (int mf = 0; mf < 4; ++mf)
#pragma unroll
                for (int nf = 0; nf < 4; ++nf) {
                    acck[mf][nf] = __builtin_amdgcn_mfma_f32_16x16x32_bf16(af[mf], wzr[kk][nf], acck[mf][nf], 0, 0, 0);
                    accp[mf][nf] = __builtin_amdgcn_mfma_f32_16x16x32_bf16(af[mf], whr[kk][nf], accp[mf][nf], 0, 0, 0);
                }
        }
        // (4) one barrier per K-step: drains next-tile stage (overlapped with MFMA)
        __syncthreads();
    }

    // Epilogue. C/D layout: col=lane&15, row=(lane>>4)*4+j  [m89-verified].
    // chunk = bx*2 + wm (64 rows). pk frag: uint4 of 4 packed half2(a,b), j=0..3.
    const int chunk = blockIdx.x * 2 + wm;
#pragma unroll
    for (int nf = 0; nf < 4; ++nf) {
        int h = n0 + wn * 64 + nf * 16 + lr;
        float bzv = bz[h], bhv = bh[h];
        float Acomb = 1.f, Bcomb = 0.f;   // composed over mf (time-ascending)
#pragma unroll
        for (int mf = 0; mf < 4; ++mf) {
            float As = 1.f, Bs = 0.f;     // this thread's 4-row segment
            uint4 ov;
#pragma unroll
            for (int j = 0; j < 4; ++j) {
                float kv = acck[mf][nf][j] + bzv;
                float pv = accp[mf][nf][j] + bhv;
                float av = 1.0f / (1.0f + __expf(kv));           // 1-z = sigmoid(-k)
                float zv = 1.0f - av;
                float gv = (pv >= 0.0f) ? (pv + 0.5f) : (1.0f / (1.0f + __expf(-pv)));
                float bvv = zv * gv;
                __half2 hp = __floats2half2_rn(av, bvv);
                ((unsigned*)&ov)[j] = *(unsigned*)&hp;
                Bs = fmaf(av, Bs, bvv);
                As *= av;
            }
            pkf[(size_t)chunk * 8192 + ((size_t)(by * 2 + wn) * 4 + nf) * 256 + mf * 64 + lane] = ov;
            // compose the 4 lane-group segments in time order (lg ascending)
            float Ag = 1.f, Bg = 0.f;
#pragma unroll
            for (int g = 0; g < 4; ++g) {
                float Ai = __shfl(As, lr + g * 16, 64);
                float Bi = __shfl(Bs, lr + g * 16, 64);
                Bg = fmaf(Ai, Bg, Bi);
                Ag *= Ai;
            }
            Bcomb = fmaf(Ag, Bcomb, Bg);
            Acomb *= Ag;
        }
        if (lg == 0) {
            agg[(size_t)chunk * 512 + h] = make_float2(Acomb, Bcomb);
        }
    }
}

// Phase 2: sequential scan over chunk aggregates, emitting carry-in per chunk.
__global__ void scan_p2(const float* __restrict__ h0, const float2* __restrict__ agg,
                        float* __restrict__ carry) {
    int g = blockIdx.x * 256 + threadIdx.x;   // 0..2047
    int b = g >> 9, h = g & 511;
    float v = h0[b * 512 + h];
    float s = (v >= 0.f) ? (v + 0.5f) : (1.f / (1.f + __expf(-v)));   // g(h_0)
    for (int c = 0; c < NC; ++c) {
        size_t o = ((size_t)(b * NC + c)) * 512 + h;
        carry[o] = s;
        float2 ab = agg[o];
        s = fmaf(ab.x, s, ab.y);
    }
}

// Phase 3: replay recurrence within chunk from frag-ordered half2 (a,b), write h.
// Thread tid: lr=tid&15, nf=(tid>>4)&3, w=tid>>6; handles h = w*64+nf*16+lr and h+256.
__global__ void scan_p3(const float* __restrict__ carry, const uint4* __restrict__ pkf,
                        float* __restrict__ out) {
    int c = blockIdx.x, b = blockIdx.y;
    int tid = threadIdx.x;
    int lr = tid & 15, nf = (tid >> 4) & 3, w = tid >> 6;
    int ha = w * 64 + nf * 16 + lr;
    int hb = ha + 256;
    size_t co = (size_t)(b * NC + c) * 512;
    float s0 = carry[co + ha], s1 = carry[co + hb];
    size_t cb = (size_t)(b * NC + c) * 8192;
    size_t ob = ((size_t)b * LL + (size_t)c * 64) * 512;
#pragma unroll
    for (int mf = 0; mf < 4; ++mf) {
#pragma unroll
        for (int lg = 0; lg < 4; ++lg) {
            uint4 fa = pkf[cb + (size_t)w * 1024 + nf * 256 + mf * 64 + lg * 16 + lr];
            uint4 fb = pkf[cb + (size_t)(w + 4) * 1024 + nf * 256 + mf * 64 + lg * 16 + lr];
#pragma unroll
            for (int j = 0; j < 4; ++j) {
                int t = mf * 16 + lg * 4 + j;
                unsigned ua = ((unsigned*)&fa)[j];
                unsigned ub = ((unsigned*)&fb)[j];
                float2 ab0 = __half22float2(*(__half2*)&ua);
                float2 ab1 = __half22float2(*(__half2*)&ub);
                s0 = fmaf(ab0.x, s0, ab0.y);
                s1 = fmaf(ab1.x, s1, ab1.y);
                out[ob + (size_t)t * 512 + ha] = s0;
                out[ob + (size_t)t * 512 + hb] = s1;
            }
        }
    }
}

extern "C" void kernel_launch(void* const* d_in, const int* in_sizes, int n_in,
                              void* d_out, int out_size, void* d_ws, size_t ws_size,
                              hipStream_t stream) {
    const float* x  = (const float*)d_in[0];
    const float* h0 = (const float*)d_in[1];
    const float* Wz = (const float*)d_in[2];
    const float* bz = (const float*)d_in[3];
    const float* Wh = (const float*)d_in[4];
    const float* bh = (const float*)d_in[5];
    float* out = (float*)d_out;

    // workspace layout (~100 MB)
    unsigned short* xs  = (unsigned short*)d_ws;                 // 32 MB
    unsigned short* wzf = xs + (size_t)MM * 512;                 // 0.5 MB
    unsigned short* whf = wzf + (size_t)512 * 512;               // 0.5 MB
    uint4* pkf   = (uint4*)(whf + (size_t)512 * 512);            // 64 MB
    float2* agg  = (float2*)((char*)pkf + (size_t)MM * 512 * 4); // 2 MB
    float* carry = (float*)(agg + (size_t)BB * NC * 512);        // 1 MB

    cvt_swz<<<8192, 256, 0, stream>>>(x, xs, MM);
    cvt_wfrag<<<256, 256, 0, stream>>>(Wz, Wh, wzf, whf);
    gemm_gate<<<dim3(256, 4), 256, 0, stream>>>(xs, wzf, whf, bz, bh, pkf, agg);
    scan_p2<<<8, 256, 0, stream>>>(h0, agg, carry);
    scan_p3<<<dim3(NC, BB), 256, 0, stream>>>(carry, pkf, out);
}